// Round 8
// baseline (374.816 us; speedup 1.0000x reference)
//
#include <hip/hip_runtime.h>

typedef unsigned long long u64;
typedef _Float16 f16;
typedef f16 f16x8 __attribute__((ext_vector_type(8)));
typedef f16 f16x4 __attribute__((ext_vector_type(4)));
typedef float f32x4 __attribute__((ext_vector_type(4)));

#define TOK 16384
#define KK 8192
#define DD 256

#define BM 256
#define BN 256
#define BK 64
#define NIT 6         // 12 K-tiles (K=768 = 3 limb products x 256), 2 per iteration

#define SCALE 4096.0f                 // 2^12, exact
#define DESCALE (1.0f/8388608.0f)     // 2^-23 = 2^-24 (limb^2) * 2 (ref's 2*dot)

// ---------------- e2[k] = sum_d emb[d][k]^2 (bit-identical all rounds) --------
__global__ void vq_e2_kernel(const float* __restrict__ emb, float* __restrict__ e2,
                             int* __restrict__ counts, float* __restrict__ nsum) {
    int k = blockIdx.x * 256 + threadIdx.x;          // 32 blocks
    float s = 0.0f;
    for (int d = 0; d < DD; d++) {
        float v = emb[(size_t)d * KK + k];
        s = fmaf(v, v, s);
    }
    e2[k] = s;
    counts[k] = 0;
    if (k == 0) *nsum = 0.0f;
}

// ------- fused: x2[t] + fp16 limb split of x -> A rows [xh(256)|xl(256)] ------
__global__ void vq_x2split_kernel(const float* __restrict__ x, float* __restrict__ x2,
                                  f16* __restrict__ A, float* __restrict__ sums,
                                  u64* __restrict__ best) {
    int gid = blockIdx.x * 256 + threadIdx.x;        // 4096 blocks
    sums[gid] = 0.0f;
    sums[gid + 1048576] = 0.0f;
    if (gid < TOK) best[gid] = 0xFFFFFFFFFFFFFFFFULL;
    int t = gid >> 6;                                // wave per token
    int lane = threadIdx.x & 63;
    float4 v = *(const float4*)(x + (size_t)t * DD + lane * 4);
    f16x4 h, l;
    float s;
    s = v.x * SCALE; h.x = (f16)s; l.x = (f16)(s - (float)h.x);
    s = v.y * SCALE; h.y = (f16)s; l.y = (f16)(s - (float)h.y);
    s = v.z * SCALE; h.z = (f16)s; l.z = (f16)(s - (float)h.z);
    s = v.w * SCALE; h.w = (f16)s; l.w = (f16)(s - (float)h.w);
    *(f16x4*)(A + (size_t)t * 512 + lane * 4) = h;
    *(f16x4*)(A + (size_t)t * 512 + 256 + lane * 4) = l;
    float p = v.x * v.x + v.y * v.y + v.z * v.z + v.w * v.w;
#pragma unroll
    for (int off = 32; off > 0; off >>= 1) p += __shfl_down(p, off, 64);
    if (lane == 0) x2[t] = p;
}

// ---- transpose emb -> embT (fp32) + limb split -> B rows [eh(256)|el(256)] ----
__global__ void vq_trsplit_kernel(const float* __restrict__ emb, float* __restrict__ embT,
                                  f16* __restrict__ B) {
    __shared__ float tile[32][33];
    int tx = threadIdx.x & 31, ty = threadIdx.x >> 5;    // 32x8 threads
    int k0 = blockIdx.x * 32, d0 = blockIdx.y * 32;      // grid (256, 8)
#pragma unroll
    for (int j = 0; j < 4; j++) {
        int d = ty * 4 + j;
        tile[d][tx] = emb[(size_t)(d0 + d) * KK + k0 + tx];
    }
    __syncthreads();
#pragma unroll
    for (int j = 0; j < 4; j++) {
        int k = ty * 4 + j;
        float v = tile[tx][k];
        embT[(size_t)(k0 + k) * DD + d0 + tx] = v;
        float sv = v * SCALE;
        f16 h = (f16)sv;
        B[(size_t)(k0 + k) * 512 + d0 + tx] = h;
        B[(size_t)(k0 + k) * 512 + 256 + d0 + tx] = (f16)(sv - (float)h);
    }
}

// ---------------- fused distance + argmin: m201 8-phase, K=768 GEMM ----------
// A[16384][512]=[xh|xl], B[8192][512]=[eh|el]; K-tiles 0-11 map to products
// hh (pa=kt,pb=kt), lh (pa=kt,pb=kt-4), hl (pa=kt-8,pb=kt-4).
// buf0=even tiles, buf1=odd. Per tile 4 phases (C quadrants), 16 MFMA each;
// counted vmcnt(4) at phase 4/8 boundaries only. slot^=row&7 LDS swizzle.
__global__ __launch_bounds__(512, 2) void vq_argmin_kernel(
        const f16* __restrict__ Ag, const f16* __restrict__ Bg,
        const float* __restrict__ x2, const float* __restrict__ e2,
        u64* __restrict__ best) {
    extern __shared__ char lds[];          // 131072

    const int tid = threadIdx.x;
    const int lane = tid & 63;
    const int wid = tid >> 6;              // 8 waves: wr (2) x wc (4)
    const int wr = wid >> 2;
    const int wc = wid & 3;
    const int lrow = lane & 15;
    const int kg = lane >> 4;
    const int k0 = blockIdx.x * BN;        // grid (32, 64)
    const int t0 = blockIdx.y * BM;

    // ds_read: swizzled 16B slot offsets for ksteps 0/1 (slot = ks*4+kg)
    const int sl0 = ((kg)     ^ (lrow & 7)) << 4;
    const int sl1 = ((4 + kg) ^ (lrow & 7)) << 4;
    const int ardo = wr * 16384 + lrow * 128;           // + mh*8192 + mc*2048
    const int brdo = 32768 + (wc * 32 + lrow) * 128;    // + nh*16384 + nc*2048

    // staging: per-thread source/dest (linear LDS dest, pre-swizzled source)
    const int row = tid >> 3;                           // 0..63
    const int ksw16 = ((tid & 7) ^ (row & 7)) << 4;
    const int tid16 = tid << 4;
    const char* Asrc = (const char*)Ag + (size_t)(t0 + row) * 1024 + ksw16;
    const char* Bs0 = (const char*)Bg +
        (size_t)(k0 + ((row >> 5)) * 64 + (row & 31)) * 1024 + ksw16;
    const char* Bs1 = (const char*)Bg +
        (size_t)(k0 + (2 + (row >> 5)) * 64 + (row & 31)) * 1024 + ksw16;

#define GL(g, l) __builtin_amdgcn_global_load_lds( \
        (const __attribute__((address_space(1))) unsigned int*)(g), \
        (__attribute__((address_space(3))) unsigned int*)(l), 16, 0, 0)
#define STAGE_A(qa, kt, b)  GL(Asrc + (qa)*65536 + ((kt) >= 8 ? (kt)-8 : (kt))*128, \
                               lds + (b)*65536 + (qa)*8192 + tid16)
#define STAGE_B(nh, g, kt, b) GL(((g) ? Bs1 : Bs0) + (nh)*32768 + ((kt) >= 4 ? (kt)-4 : (kt))*128, \
                               lds + (b)*65536 + 32768 + (nh)*16384 + (g)*8192 + tid16)
#define MF(x, y, z) __builtin_amdgcn_mfma_f32_16x16x32_f16(x, y, z, 0, 0, 0)
#define BARR __builtin_amdgcn_s_barrier()
#define WLG0 asm volatile("s_waitcnt lgkmcnt(0)" ::: "memory")
#define PRIO1 __builtin_amdgcn_s_setprio(1)
#define PRIO0 __builtin_amdgcn_s_setprio(0)
#define LDA(mh) { const char* _p = cb + ardo + (mh)*8192; \
    af[0][0]=*(const f16x8*)(_p+sl0);      af[0][1]=*(const f16x8*)(_p+sl1); \
    af[1][0]=*(const f16x8*)(_p+2048+sl0); af[1][1]=*(const f16x8*)(_p+2048+sl1); \
    af[2][0]=*(const f16x8*)(_p+4096+sl0); af[2][1]=*(const f16x8*)(_p+4096+sl1); \
    af[3][0]=*(const f16x8*)(_p+6144+sl0); af[3][1]=*(const f16x8*)(_p+6144+sl1); }
#define LDB(nh) { const char* _p = cb + brdo + (nh)*16384; \
    bf[0][0]=*(const f16x8*)(_p+sl0);      bf[0][1]=*(const f16x8*)(_p+sl1); \
    bf[1][0]=*(const f16x8*)(_p+2048+sl0); bf[1][1]=*(const f16x8*)(_p+2048+sl1); }
#define MMQ(MB, NB) { \
    acc[MB][NB]    =MF(af[0][0],bf[0][0],acc[MB][NB]);     acc[MB][NB]    =MF(af[0][1],bf[0][1],acc[MB][NB]); \
    acc[MB][NB+1]  =MF(af[0][0],bf[1][0],acc[MB][NB+1]);   acc[MB][NB+1]  =MF(af[0][1],bf[1][1],acc[MB][NB+1]); \
    acc[MB+1][NB]  =MF(af[1][0],bf[0][0],acc[MB+1][NB]);   acc[MB+1][NB]  =MF(af[1][1],bf[0][1],acc[MB+1][NB]); \
    acc[MB+1][NB+1]=MF(af[1][0],bf[1][0],acc[MB+1][NB+1]); acc[MB+1][NB+1]=MF(af[1][1],bf[1][1],acc[MB+1][NB+1]); \
    acc[MB+2][NB]  =MF(af[2][0],bf[0][0],acc[MB+2][NB]);   acc[MB+2][NB]  =MF(af[2][1],bf[0][1],acc[MB+2][NB]); \
    acc[MB+2][NB+1]=MF(af[2][0],bf[1][0],acc[MB+2][NB+1]); acc[MB+2][NB+1]=MF(af[2][1],bf[1][1],acc[MB+2][NB+1]); \
    acc[MB+3][NB]  =MF(af[3][0],bf[0][0],acc[MB+3][NB]);   acc[MB+3][NB]  =MF(af[3][1],bf[0][1],acc[MB+3][NB]); \
    acc[MB+3][NB+1]=MF(af[3][0],bf[1][0],acc[MB+3][NB+1]); acc[MB+3][NB+1]=MF(af[3][1],bf[1][1],acc[MB+3][NB+1]); }

    f32x4 acc[8][4];
#pragma unroll
    for (int m = 0; m < 8; m++)
#pragma unroll
        for (int n = 0; n < 4; n++) {
            f32x4 z = {0.0f, 0.0f, 0.0f, 0.0f};
            acc[m][n] = z;
        }
    f16x8 af[4][2], bf[2][2];

    // prologue: tile0 full (8) -> buf0, tile1 A quarters (4) -> buf1
    STAGE_A(0, 0, 0); STAGE_A(1, 0, 0); STAGE_A(2, 0, 0); STAGE_A(3, 0, 0);
    STAGE_B(0, 0, 0, 0); STAGE_B(0, 1, 0, 0); STAGE_B(1, 0, 0, 0); STAGE_B(1, 1, 0, 0);
    STAGE_A(0, 1, 1); STAGE_A(1, 1, 1); STAGE_A(2, 1, 1); STAGE_A(3, 1, 1);
    asm volatile("s_waitcnt vmcnt(4)" ::: "memory");
    BARR;

    for (int i = 0; i < NIT; i++) {
        const int ktb = 2 * i + 1, kt2 = 2 * i + 2, kt3 = 2 * i + 3;
        const bool st = (i < NIT - 1);
        const char* cb = lds;                      // ---- even tile, buf0 ----
        // P1 (m0,n0)
        LDA(0); LDB(0);
        STAGE_B(1, 0, ktb, 1); STAGE_B(1, 1, ktb, 1);
        asm volatile("s_waitcnt lgkmcnt(8)" ::: "memory");
        BARR; WLG0; PRIO1; MMQ(0, 0); PRIO0; BARR;
        // P2 (m0,n1)
        LDB(1);
        STAGE_B(0, 0, ktb, 1); STAGE_B(0, 1, ktb, 1);
        if (st) { STAGE_A(0, kt2, 0); STAGE_A(2, kt2, 0); }
        BARR; WLG0; PRIO1; MMQ(0, 2); PRIO0; BARR;
        // P3 (m1,n1)
        LDA(1);
        BARR; WLG0; PRIO1; MMQ(4, 2); PRIO0; BARR;
        // P4 (m1,n0) + tile boundary (counted vmcnt)
        LDB(0);
        if (st) { STAGE_A(1, kt2, 0); STAGE_A(3, kt2, 0); }
        BARR; WLG0; PRIO1; MMQ(4, 0); PRIO0;
        if (st) asm volatile("s_waitcnt vmcnt(4)" ::: "memory");
        else    asm volatile("s_waitcnt vmcnt(0)" ::: "memory");
        BARR;

        cb = lds + 65536;                          // ---- odd tile, buf1 ----
        // P5 (m0,n0)
        LDA(0); LDB(0);
        if (st) { STAGE_B(1, 0, kt2, 0); STAGE_B(1, 1, kt2, 0); }
        asm volatile("s_waitcnt lgkmcnt(8)" ::: "memory");
        BARR; WLG0; PRIO1; MMQ(0, 0); PRIO0; BARR;
        // P6 (m0,n1)
        LDB(1);
        if (st) { STAGE_B(0, 0, kt2, 0); STAGE_B(0, 1, kt2, 0); }
        BARR; WLG0; PRIO1; MMQ(0, 2); PRIO0; BARR;
        // P7 (m1,n1)
        LDA(1);
        if (st) { STAGE_A(0, kt3, 1); STAGE_A(2, kt3, 1); }
        BARR; WLG0; PRIO1; MMQ(4, 2); PRIO0; BARR;
        // P8 (m1,n0) + boundary
        LDB(0);
        if (st) { STAGE_A(1, kt3, 1); STAGE_A(3, kt3, 1); }
        BARR; WLG0; PRIO1; MMQ(4, 0); PRIO0;
        if (st) asm volatile("s_waitcnt vmcnt(4)" ::: "memory");
        BARR;
    }
#undef GL
#undef STAGE_A
#undef STAGE_B

    // ---------------- epilogue: distances + argmin ----------------
    // C/D: col = lane&15, row = (lane>>4)*4 + reg; cell (m,n): rows wr*128 +
    // (m>>2)*64 + (m&3)*16, cols wc*64 + (n>>1)*32 + (n&1)*16.
    __syncthreads();
    u64* red = (u64*)lds;
    if (tid < BM) red[tid] = 0xFFFFFFFFFFFFFFFFULL;
    __syncthreads();

    float se2[4];
#pragma unroll
    for (int n = 0; n < 4; n++)
        se2[n] = e2[k0 + wc * 64 + (n >> 1) * 32 + (n & 1) * 16 + lrow];

#pragma unroll
    for (int m = 0; m < 8; m++) {
#pragma unroll
        for (int r = 0; r < 4; r++) {
            int rowl = wr * 128 + (m >> 2) * 64 + (m & 3) * 16 + kg * 4 + r;
            float sx2 = x2[t0 + rowl];
            u64 b = 0xFFFFFFFFFFFFFFFFULL;
#pragma unroll
            for (int n = 0; n < 4; n++) {
                int kgl = k0 + wc * 64 + (n >> 1) * 32 + (n & 1) * 16 + lrow;
                float s = sx2 + se2[n];            // rounded add (matches ref)
                float td = acc[m][n][r] * DESCALE; // exact pow2 scale
                asm volatile("" : "+v"(td));
                float dist = s - td;               // rounded sub (matches ref)
                u64 pk = ((u64)__float_as_uint(dist) << 32) | (unsigned)kgl;
                b = pk < b ? pk : b;
            }
#pragma unroll
            for (int off2 = 1; off2 < 16; off2 <<= 1) {
                u64 o = __shfl_xor(b, off2, 64);
                b = o < b ? o : b;
            }
            if (lrow == 0) atomicMin(&red[rowl], b);
        }
    }
    __syncthreads();
    if (tid < BM) atomicMin(&best[t0 + tid], red[tid]);
}

// ---------------- extract indices + counts ----------------
__global__ void vq_indices_kernel(const u64* __restrict__ best, int* __restrict__ indices,
                                  int* __restrict__ counts) {
    int t = blockIdx.x * 256 + threadIdx.x;
    int idx = (int)(best[t] & 0xFFFFFFFFULL);
    indices[t] = idx;
    atomicAdd(&counts[idx], 1);
}

// ---------------- new_N + N_sum ----------------
__global__ void vq_newN_kernel(const float* __restrict__ N, const int* __restrict__ counts,
                               float* __restrict__ outN, float* __restrict__ nsum) {
    int k = blockIdx.x * 256 + threadIdx.x;
    float a = 0.99f * N[k];
    float b = 0.01f * (float)counts[k];
    float nN = a + b;
    outN[k] = nN;
    float s = nN;
#pragma unroll
    for (int off = 32; off > 0; off >>= 1) s += __shfl_down(s, off, 64);
    __shared__ float wsum[4];
    int lane = threadIdx.x & 63, w = threadIdx.x >> 6;
    if (lane == 0) wsum[w] = s;
    __syncthreads();
    if (threadIdx.x == 0) atomicAdd(nsum, wsum[0] + wsum[1] + wsum[2] + wsum[3]);
}

// ---------------- fused: quantized_st write + sums scatter ----------------
__global__ void vq_gs_kernel(const float* __restrict__ x, const float* __restrict__ embT,
                             const int* __restrict__ indices, float* __restrict__ out0,
                             float* __restrict__ sums) {
    int t = blockIdx.x * 4 + (threadIdx.x >> 6);     // 4096 blocks, wave per token
    int lane = threadIdx.x & 63;
    int idx = indices[t];
    size_t o = (size_t)t * DD + lane * 4;
    float4 xv = *(const float4*)(x + o);
    float4 qv = *(const float4*)(embT + (size_t)idx * DD + lane * 4);
    float4 ov;
    ov.x = xv.x + (qv.x - xv.x);
    ov.y = xv.y + (qv.y - xv.y);
    ov.z = xv.z + (qv.z - xv.z);
    ov.w = xv.w + (qv.w - xv.w);
    *(float4*)(out0 + o) = ov;
    float* base = sums + (size_t)idx * DD + lane * 4;
    atomicAdd(base + 0, xv.x);
    atomicAdd(base + 1, xv.y);
    atomicAdd(base + 2, xv.z);
    atomicAdd(base + 3, xv.w);
}

// ---------------- new_m and new_embeddings ----------------
__global__ void vq_final_kernel(const float* __restrict__ m, const float* __restrict__ sums,
                                const float* __restrict__ outN, const float* __restrict__ nsum,
                                float* __restrict__ outEmb, float* __restrict__ outM) {
    int gid = blockIdx.x * 256 + threadIdx.x;
    int k = gid & (KK - 1);
    int d = gid >> 13;
    float Nsum = *nsum;
    float nN = outN[k];
    float scaled = (nN + 1e-5f) / (Nsum + 0.08192f) * Nsum;
    float a = 0.99f * m[gid];
    float b = 0.01f * sums[(size_t)k * DD + d];
    float mv = a + b;
    outM[gid] = mv;
    outEmb[gid] = mv / scaled;
}

extern "C" void kernel_launch(void* const* d_in, const int* in_sizes, int n_in,
                              void* d_out, int out_size, void* d_ws, size_t ws_size,
                              hipStream_t stream) {
    const float* x   = (const float*)d_in[0];   // [16384][256]
    const float* emb = (const float*)d_in[1];   // [256][8192]
    const float* Nin = (const float*)d_in[2];   // [8192]
    const float* min = (const float*)d_in[3];   // [256][8192]

    float* out0   = (float*)d_out;              // quantized_st  [4194304]
    float* outEmb = out0 + 4194304;             // new_embeddings [2097152]
    float* outN   = outEmb + 2097152;           // new_N [8192]
    float* outM   = outN + 8192;                // new_m [2097152]

    // workspace (floats)
    float* ws      = (float*)d_ws;
    float* sums    = ws;                        // 2097152
    float* e2buf   = ws + 2097152;              // 8192
    float* x2buf   = e2buf + 8192;              // 16384
    u64*   best    = (u64*)(x2buf + 16384);     // 16384 u64
    int*   idxbuf  = (int*)(best + 16384);      // 16384
    int*   counts  = idxbuf + 16384;            // 8192
    float* nsum    = (float*)(counts + 8192);   // 1

    // GEMM operand panels staged in output regions written later:
    f16* Ab   = (f16*)out0;                     // [16384][512] = [xh|xl], 16 MB
    f16* Bb   = (f16*)outEmb;                   // [8192][512]  = [eh|el],  8 MB
    float* embT = outM;                         // 8 MB fp32, overwritten last

    vq_e2_kernel<<<32, 256, 0, stream>>>(emb, e2buf, counts, nsum);
    vq_x2split_kernel<<<4096, 256, 0, stream>>>(x, x2buf, Ab, sums, best);
    vq_trsplit_kernel<<<dim3(256, 8), 256, 0, stream>>>(emb, embT, Bb);
    vq_argmin_kernel<<<dim3(KK / BN, TOK / BM), 512, 131072, stream>>>(
        Ab, Bb, x2buf, e2buf, best);
    vq_indices_kernel<<<64, 256, 0, stream>>>(best, idxbuf, counts);
    vq_newN_kernel<<<32, 256, 0, stream>>>(Nin, counts, outN, nsum);
    vq_gs_kernel<<<4096, 256, 0, stream>>>(x, embT, idxbuf, out0, sums);
    vq_final_kernel<<<8192, 256, 0, stream>>>(min, sums, outN, nsum, outEmb, outM);
}

// Round 9
// 374.086 us; speedup vs baseline: 1.0020x; 1.0020x over previous
//
#include <hip/hip_runtime.h>

typedef unsigned long long u64;
typedef _Float16 f16;
typedef f16 f16x8 __attribute__((ext_vector_type(8)));
typedef f16 f16x4 __attribute__((ext_vector_type(4)));
typedef float f32x4 __attribute__((ext_vector_type(4)));

#define TOK 16384
#define KK 8192
#define DD 256

#define BM 256
#define BN 256
#define BK 64
#define NIT 6         // 12 K-tiles (K=768 = 3 limb products x 256), 2 per iteration

#define SCALE 4096.0f                 // 2^12, exact
#define DESCALE (1.0f/8388608.0f)     // 2^-23 = 2^-24 (limb^2) * 2 (ref's 2*dot)

// ---------------- e2[k] = sum_d emb[d][k]^2 (bit-identical all rounds) --------
__global__ void vq_e2_kernel(const float* __restrict__ emb, float* __restrict__ e2,
                             int* __restrict__ counts, float* __restrict__ nsum) {
    int k = blockIdx.x * 256 + threadIdx.x;          // 32 blocks
    float s = 0.0f;
    for (int d = 0; d < DD; d++) {
        float v = emb[(size_t)d * KK + k];
        s = fmaf(v, v, s);
    }
    e2[k] = s;
    counts[k] = 0;
    if (k == 0) *nsum = 0.0f;
}

// ------- fused: x2[t] + fp16 limb split of x -> A rows [xh(256)|xl(256)] ------
__global__ void vq_x2split_kernel(const float* __restrict__ x, float* __restrict__ x2,
                                  f16* __restrict__ A, float* __restrict__ sums,
                                  u64* __restrict__ best) {
    int gid = blockIdx.x * 256 + threadIdx.x;        // 4096 blocks
    sums[gid] = 0.0f;
    sums[gid + 1048576] = 0.0f;
    if (gid < TOK) best[gid] = 0xFFFFFFFFFFFFFFFFULL;
    int t = gid >> 6;                                // wave per token
    int lane = threadIdx.x & 63;
    float4 v = *(const float4*)(x + (size_t)t * DD + lane * 4);
    f16x4 h, l;
    float s;
    s = v.x * SCALE; h.x = (f16)s; l.x = (f16)(s - (float)h.x);
    s = v.y * SCALE; h.y = (f16)s; l.y = (f16)(s - (float)h.y);
    s = v.z * SCALE; h.z = (f16)s; l.z = (f16)(s - (float)h.z);
    s = v.w * SCALE; h.w = (f16)s; l.w = (f16)(s - (float)h.w);
    *(f16x4*)(A + (size_t)t * 512 + lane * 4) = h;
    *(f16x4*)(A + (size_t)t * 512 + 256 + lane * 4) = l;
    float p = v.x * v.x + v.y * v.y + v.z * v.z + v.w * v.w;
#pragma unroll
    for (int off = 32; off > 0; off >>= 1) p += __shfl_down(p, off, 64);
    if (lane == 0) x2[t] = p;
}

// ---- transpose emb -> embT (fp32) + limb split -> B rows [eh(256)|el(256)] ----
__global__ void vq_trsplit_kernel(const float* __restrict__ emb, float* __restrict__ embT,
                                  f16* __restrict__ B) {
    __shared__ float tile[32][33];
    int tx = threadIdx.x & 31, ty = threadIdx.x >> 5;    // 32x8 threads
    int k0 = blockIdx.x * 32, d0 = blockIdx.y * 32;      // grid (256, 8)
#pragma unroll
    for (int j = 0; j < 4; j++) {
        int d = ty * 4 + j;
        tile[d][tx] = emb[(size_t)(d0 + d) * KK + k0 + tx];
    }
    __syncthreads();
#pragma unroll
    for (int j = 0; j < 4; j++) {
        int k = ty * 4 + j;
        float v = tile[tx][k];
        embT[(size_t)(k0 + k) * DD + d0 + tx] = v;
        float sv = v * SCALE;
        f16 h = (f16)sv;
        B[(size_t)(k0 + k) * 512 + d0 + tx] = h;
        B[(size_t)(k0 + k) * 512 + 256 + d0 + tx] = (f16)(sv - (float)h);
    }
}

// ---------------- fused distance + argmin: m201 8-phase, K=768 GEMM ----------
// Identical schedule/numerics to round 8; NIT loop FULLY UNROLLED so all kt
// staging offsets are compile-time immediates (r8 spilled: runtime kt mapping
// kept ~12 addresses live across barriers -> over the 128-VGPR cap).
__global__ __launch_bounds__(512, 2) void vq_argmin_kernel(
        const f16* __restrict__ Ag, const f16* __restrict__ Bg,
        const float* __restrict__ x2, const float* __restrict__ e2,
        u64* __restrict__ best) {
    extern __shared__ char lds[];          // 131072

    const int tid = threadIdx.x;
    const int lane = tid & 63;
    const int wid = tid >> 6;              // 8 waves: wr (2) x wc (4)
    const int wr = wid >> 2;
    const int wc = wid & 3;
    const int lrow = lane & 15;
    const int kg = lane >> 4;
    const int k0 = blockIdx.x * BN;        // grid (32, 64)
    const int t0 = blockIdx.y * BM;

    // ds_read: swizzled 16B slot offsets for ksteps 0/1 (slot = ks*4+kg)
    const int sl0 = ((kg)     ^ (lrow & 7)) << 4;
    const int sl1 = ((4 + kg) ^ (lrow & 7)) << 4;
    const int ardo = wr * 16384 + lrow * 128;           // + mh*8192 + mc*2048
    const int brdo = 32768 + (wc * 32 + lrow) * 128;    // + nh*16384 + nc*2048

    // staging: per-thread source/dest (linear LDS dest, pre-swizzled source)
    const int row = tid >> 3;                           // 0..63
    const int ksw16 = ((tid & 7) ^ (row & 7)) << 4;
    const int tid16 = tid << 4;
    const char* Asrc = (const char*)Ag + (size_t)(t0 + row) * 1024 + ksw16;
    const char* Bs0 = (const char*)Bg +
        (size_t)(k0 + ((row >> 5)) * 64 + (row & 31)) * 1024 + ksw16;
    const char* Bs1 = (const char*)Bg +
        (size_t)(k0 + (2 + (row >> 5)) * 64 + (row & 31)) * 1024 + ksw16;

#define GL(g, l) __builtin_amdgcn_global_load_lds( \
        (const __attribute__((address_space(1))) unsigned int*)(g), \
        (__attribute__((address_space(3))) unsigned int*)(l), 16, 0, 0)
#define STAGE_A(qa, kt, b)  GL(Asrc + (qa)*65536 + ((kt) >= 8 ? (kt)-8 : (kt))*128, \
                               lds + (b)*65536 + (qa)*8192 + tid16)
#define STAGE_B(nh, g, kt, b) GL(((g) ? Bs1 : Bs0) + (nh)*32768 + ((kt) >= 4 ? (kt)-4 : (kt))*128, \
                               lds + (b)*65536 + 32768 + (nh)*16384 + (g)*8192 + tid16)
#define MF(x, y, z) __builtin_amdgcn_mfma_f32_16x16x32_f16(x, y, z, 0, 0, 0)
#define BARR __builtin_amdgcn_s_barrier()
#define WLG0 asm volatile("s_waitcnt lgkmcnt(0)" ::: "memory")
#define PRIO1 __builtin_amdgcn_s_setprio(1)
#define PRIO0 __builtin_amdgcn_s_setprio(0)
#define LDA(mh) { const char* _p = cb + ardo + (mh)*8192; \
    af[0][0]=*(const f16x8*)(_p+sl0);      af[0][1]=*(const f16x8*)(_p+sl1); \
    af[1][0]=*(const f16x8*)(_p+2048+sl0); af[1][1]=*(const f16x8*)(_p+2048+sl1); \
    af[2][0]=*(const f16x8*)(_p+4096+sl0); af[2][1]=*(const f16x8*)(_p+4096+sl1); \
    af[3][0]=*(const f16x8*)(_p+6144+sl0); af[3][1]=*(const f16x8*)(_p+6144+sl1); }
#define LDB(nh) { const char* _p = cb + brdo + (nh)*16384; \
    bf[0][0]=*(const f16x8*)(_p+sl0);      bf[0][1]=*(const f16x8*)(_p+sl1); \
    bf[1][0]=*(const f16x8*)(_p+2048+sl0); bf[1][1]=*(const f16x8*)(_p+2048+sl1); }
#define MMQ(MB, NB) { \
    acc[MB][NB]    =MF(af[0][0],bf[0][0],acc[MB][NB]);     acc[MB][NB]    =MF(af[0][1],bf[0][1],acc[MB][NB]); \
    acc[MB][NB+1]  =MF(af[0][0],bf[1][0],acc[MB][NB+1]);   acc[MB][NB+1]  =MF(af[0][1],bf[1][1],acc[MB][NB+1]); \
    acc[MB+1][NB]  =MF(af[1][0],bf[0][0],acc[MB+1][NB]);   acc[MB+1][NB]  =MF(af[1][1],bf[0][1],acc[MB+1][NB]); \
    acc[MB+1][NB+1]=MF(af[1][0],bf[1][0],acc[MB+1][NB+1]); acc[MB+1][NB+1]=MF(af[1][1],bf[1][1],acc[MB+1][NB+1]); \
    acc[MB+2][NB]  =MF(af[2][0],bf[0][0],acc[MB+2][NB]);   acc[MB+2][NB]  =MF(af[2][1],bf[0][1],acc[MB+2][NB]); \
    acc[MB+2][NB+1]=MF(af[2][0],bf[1][0],acc[MB+2][NB+1]); acc[MB+2][NB+1]=MF(af[2][1],bf[1][1],acc[MB+2][NB+1]); \
    acc[MB+3][NB]  =MF(af[3][0],bf[0][0],acc[MB+3][NB]);   acc[MB+3][NB]  =MF(af[3][1],bf[0][1],acc[MB+3][NB]); \
    acc[MB+3][NB+1]=MF(af[3][0],bf[1][0],acc[MB+3][NB+1]); acc[MB+3][NB+1]=MF(af[3][1],bf[1][1],acc[MB+3][NB+1]); }

    f32x4 acc[8][4];
#pragma unroll
    for (int m = 0; m < 8; m++)
#pragma unroll
        for (int n = 0; n < 4; n++) {
            f32x4 z = {0.0f, 0.0f, 0.0f, 0.0f};
            acc[m][n] = z;
        }
    f16x8 af[4][2], bf[2][2];

    // prologue: tile0 full (8) -> buf0, tile1 A quarters (4) -> buf1
    STAGE_A(0, 0, 0); STAGE_A(1, 0, 0); STAGE_A(2, 0, 0); STAGE_A(3, 0, 0);
    STAGE_B(0, 0, 0, 0); STAGE_B(0, 1, 0, 0); STAGE_B(1, 0, 0, 0); STAGE_B(1, 1, 0, 0);
    STAGE_A(0, 1, 1); STAGE_A(1, 1, 1); STAGE_A(2, 1, 1); STAGE_A(3, 1, 1);
    asm volatile("s_waitcnt vmcnt(4)" ::: "memory");
    BARR;

#pragma unroll
    for (int i = 0; i < NIT; i++) {
        const int ktb = 2 * i + 1, kt2 = 2 * i + 2, kt3 = 2 * i + 3;
        const bool st = (i < NIT - 1);
        const char* cb = lds;                      // ---- even tile, buf0 ----
        // P1 (m0,n0)
        LDA(0); LDB(0);
        STAGE_B(1, 0, ktb, 1); STAGE_B(1, 1, ktb, 1);
        asm volatile("s_waitcnt lgkmcnt(8)" ::: "memory");
        BARR; WLG0; PRIO1; MMQ(0, 0); PRIO0; BARR;
        // P2 (m0,n1)
        LDB(1);
        STAGE_B(0, 0, ktb, 1); STAGE_B(0, 1, ktb, 1);
        if (st) { STAGE_A(0, kt2, 0); STAGE_A(2, kt2, 0); }
        BARR; WLG0; PRIO1; MMQ(0, 2); PRIO0; BARR;
        // P3 (m1,n1)
        LDA(1);
        BARR; WLG0; PRIO1; MMQ(4, 2); PRIO0; BARR;
        // P4 (m1,n0) + tile boundary (counted vmcnt)
        LDB(0);
        if (st) { STAGE_A(1, kt2, 0); STAGE_A(3, kt2, 0); }
        BARR; WLG0; PRIO1; MMQ(4, 0); PRIO0;
        if (st) asm volatile("s_waitcnt vmcnt(4)" ::: "memory");
        else    asm volatile("s_waitcnt vmcnt(0)" ::: "memory");
        BARR;

        cb = lds + 65536;                          // ---- odd tile, buf1 ----
        // P5 (m0,n0)
        LDA(0); LDB(0);
        if (st) { STAGE_B(1, 0, kt2, 0); STAGE_B(1, 1, kt2, 0); }
        asm volatile("s_waitcnt lgkmcnt(8)" ::: "memory");
        BARR; WLG0; PRIO1; MMQ(0, 0); PRIO0; BARR;
        // P6 (m0,n1)
        LDB(1);
        if (st) { STAGE_B(0, 0, kt2, 0); STAGE_B(0, 1, kt2, 0); }
        BARR; WLG0; PRIO1; MMQ(0, 2); PRIO0; BARR;
        // P7 (m1,n1)
        LDA(1);
        if (st) { STAGE_A(0, kt3, 1); STAGE_A(2, kt3, 1); }
        BARR; WLG0; PRIO1; MMQ(4, 2); PRIO0; BARR;
        // P8 (m1,n0) + boundary
        LDB(0);
        if (st) { STAGE_A(1, kt3, 1); STAGE_A(3, kt3, 1); }
        BARR; WLG0; PRIO1; MMQ(4, 0); PRIO0;
        if (st) asm volatile("s_waitcnt vmcnt(4)" ::: "memory");
        BARR;
    }
#undef GL
#undef STAGE_A
#undef STAGE_B

    // ---------------- epilogue: distances + argmin ----------------
    // C/D: col = lane&15, row = (lane>>4)*4 + reg; cell (m,n): rows wr*128 +
    // (m>>2)*64 + (m&3)*16, cols wc*64 + (n>>1)*32 + (n&1)*16.
    __syncthreads();
    u64* red = (u64*)lds;
    if (tid < BM) red[tid] = 0xFFFFFFFFFFFFFFFFULL;
    __syncthreads();

    float se2[4];
#pragma unroll
    for (int n = 0; n < 4; n++)
        se2[n] = e2[k0 + wc * 64 + (n >> 1) * 32 + (n & 1) * 16 + lrow];

#pragma unroll
    for (int m = 0; m < 8; m++) {
#pragma unroll
        for (int r = 0; r < 4; r++) {
            int rowl = wr * 128 + (m >> 2) * 64 + (m & 3) * 16 + kg * 4 + r;
            float sx2 = x2[t0 + rowl];
            u64 b = 0xFFFFFFFFFFFFFFFFULL;
#pragma unroll
            for (int n = 0; n < 4; n++) {
                int kgl = k0 + wc * 64 + (n >> 1) * 32 + (n & 1) * 16 + lrow;
                float s = sx2 + se2[n];            // rounded add (matches ref)
                float td = acc[m][n][r] * DESCALE; // exact pow2 scale
                asm volatile("" : "+v"(td));
                float dist = s - td;               // rounded sub (matches ref)
                u64 pk = ((u64)__float_as_uint(dist) << 32) | (unsigned)kgl;
                b = pk < b ? pk : b;
            }
#pragma unroll
            for (int off2 = 1; off2 < 16; off2 <<= 1) {
                u64 o = __shfl_xor(b, off2, 64);
                b = o < b ? o : b;
            }
            if (lrow == 0) atomicMin(&red[rowl], b);
        }
    }
    __syncthreads();
    if (tid < BM) atomicMin(&best[t0 + tid], red[tid]);
}

// ---------------- extract indices + counts ----------------
__global__ void vq_indices_kernel(const u64* __restrict__ best, int* __restrict__ indices,
                                  int* __restrict__ counts) {
    int t = blockIdx.x * 256 + threadIdx.x;
    int idx = (int)(best[t] & 0xFFFFFFFFULL);
    indices[t] = idx;
    atomicAdd(&counts[idx], 1);
}

// ---------------- new_N + N_sum ----------------
__global__ void vq_newN_kernel(const float* __restrict__ N, const int* __restrict__ counts,
                               float* __restrict__ outN, float* __restrict__ nsum) {
    int k = blockIdx.x * 256 + threadIdx.x;
    float a = 0.99f * N[k];
    float b = 0.01f * (float)counts[k];
    float nN = a + b;
    outN[k] = nN;
    float s = nN;
#pragma unroll
    for (int off = 32; off > 0; off >>= 1) s += __shfl_down(s, off, 64);
    __shared__ float wsum[4];
    int lane = threadIdx.x & 63, w = threadIdx.x >> 6;
    if (lane == 0) wsum[w] = s;
    __syncthreads();
    if (threadIdx.x == 0) atomicAdd(nsum, wsum[0] + wsum[1] + wsum[2] + wsum[3]);
}

// ---------------- fused: quantized_st write + sums scatter ----------------
__global__ void vq_gs_kernel(const float* __restrict__ x, const float* __restrict__ embT,
                             const int* __restrict__ indices, float* __restrict__ out0,
                             float* __restrict__ sums) {
    int t = blockIdx.x * 4 + (threadIdx.x >> 6);     // 4096 blocks, wave per token
    int lane = threadIdx.x & 63;
    int idx = indices[t];
    size_t o = (size_t)t * DD + lane * 4;
    float4 xv = *(const float4*)(x + o);
    float4 qv = *(const float4*)(embT + (size_t)idx * DD + lane * 4);
    float4 ov;
    ov.x = xv.x + (qv.x - xv.x);
    ov.y = xv.y + (qv.y - xv.y);
    ov.z = xv.z + (qv.z - xv.z);
    ov.w = xv.w + (qv.w - xv.w);
    *(float4*)(out0 + o) = ov;
    float* base = sums + (size_t)idx * DD + lane * 4;
    atomicAdd(base + 0, xv.x);
    atomicAdd(base + 1, xv.y);
    atomicAdd(base + 2, xv.z);
    atomicAdd(base + 3, xv.w);
}

// ---------------- new_m and new_embeddings ----------------
__global__ void vq_final_kernel(const float* __restrict__ m, const float* __restrict__ sums,
                                const float* __restrict__ outN, const float* __restrict__ nsum,
                                float* __restrict__ outEmb, float* __restrict__ outM) {
    int gid = blockIdx.x * 256 + threadIdx.x;
    int k = gid & (KK - 1);
    int d = gid >> 13;
    float Nsum = *nsum;
    float nN = outN[k];
    float scaled = (nN + 1e-5f) / (Nsum + 0.08192f) * Nsum;
    float a = 0.99f * m[gid];
    float b = 0.01f * sums[(size_t)k * DD + d];
    float mv = a + b;
    outM[gid] = mv;
    outEmb[gid] = mv / scaled;
}

extern "C" void kernel_launch(void* const* d_in, const int* in_sizes, int n_in,
                              void* d_out, int out_size, void* d_ws, size_t ws_size,
                              hipStream_t stream) {
    const float* x   = (const float*)d_in[0];   // [16384][256]
    const float* emb = (const float*)d_in[1];   // [256][8192]
    const float* Nin = (const float*)d_in[2];   // [8192]
    const float* min = (const float*)d_in[3];   // [256][8192]

    float* out0   = (float*)d_out;              // quantized_st  [4194304]
    float* outEmb = out0 + 4194304;             // new_embeddings [2097152]
    float* outN   = outEmb + 2097152;           // new_N [8192]
    float* outM   = outN + 8192;                // new_m [2097152]

    // workspace (floats)
    float* ws      = (float*)d_ws;
    float* sums    = ws;                        // 2097152
    float* e2buf   = ws + 2097152;              // 8192
    float* x2buf   = e2buf + 8192;              // 16384
    u64*   best    = (u64*)(x2buf + 16384);     // 16384 u64
    int*   idxbuf  = (int*)(best + 16384);      // 16384
    int*   counts  = idxbuf + 16384;            // 8192
    float* nsum    = (float*)(counts + 8192);   // 1

    // GEMM operand panels staged in output regions written later:
    f16* Ab   = (f16*)out0;                     // [16384][512] = [xh|xl], 16 MB
    f16* Bb   = (f16*)outEmb;                   // [8192][512]  = [eh|el],  8 MB
    float* embT = outM;                         // 8 MB fp32, overwritten last

    vq_e2_kernel<<<32, 256, 0, stream>>>(emb, e2buf, counts, nsum);
    vq_x2split_kernel<<<4096, 256, 0, stream>>>(x, x2buf, Ab, sums, best);
    vq_trsplit_kernel<<<dim3(256, 8), 256, 0, stream>>>(emb, embT, Bb);
    vq_argmin_kernel<<<dim3(KK / BN, TOK / BM), 512, 131072, stream>>>(
        Ab, Bb, x2buf, e2buf, best);
    vq_indices_kernel<<<64, 256, 0, stream>>>(best, idxbuf, counts);
    vq_newN_kernel<<<32, 256, 0, stream>>>(Nin, counts, outN, nsum);
    vq_gs_kernel<<<4096, 256, 0, stream>>>(x, embT, idxbuf, out0, sums);
    vq_final_kernel<<<8192, 256, 0, stream>>>(min, sums, outN, nsum, outEmb, outM);
}

// Round 12
// 333.228 us; speedup vs baseline: 1.1248x; 1.1226x over previous
//
#include <hip/hip_runtime.h>

typedef unsigned long long u64;
typedef _Float16 f16;
typedef f16 f16x8 __attribute__((ext_vector_type(8)));
typedef f16 f16x4 __attribute__((ext_vector_type(4)));
typedef float f32x4 __attribute__((ext_vector_type(4)));

#define TOK 16384
#define KK 8192
#define DD 256

#define BM 256
#define BN 256
#define BK 64
#define NIT 6         // 12 K-tiles (K=768 = 3 limb products x 256), 2 per iteration

#define SCALE 4096.0f                 // 2^12, exact
#define DESCALE (1.0f/8388608.0f)     // 2^-23 = 2^-24 (limb^2) * 2 (ref's 2*dot)

// ---------------- e2[k] = sum_d emb[d][k]^2 (bit-identical all rounds) --------
__global__ void vq_e2_kernel(const float* __restrict__ emb, float* __restrict__ e2,
                             int* __restrict__ counts, float* __restrict__ nsum) {
    int k = blockIdx.x * 256 + threadIdx.x;          // 32 blocks
    float s = 0.0f;
    for (int d = 0; d < DD; d++) {
        float v = emb[(size_t)d * KK + k];
        s = fmaf(v, v, s);
    }
    e2[k] = s;
    counts[k] = 0;
    if (k == 0) *nsum = 0.0f;
}

// ------- fused: x2[t] + fp16 limb split of x -> A rows [xh(256)|xl(256)] ------
__global__ void vq_x2split_kernel(const float* __restrict__ x, float* __restrict__ x2,
                                  f16* __restrict__ A, float* __restrict__ sums,
                                  u64* __restrict__ best) {
    int gid = blockIdx.x * 256 + threadIdx.x;        // 4096 blocks
    sums[gid] = 0.0f;
    sums[gid + 1048576] = 0.0f;
    if (gid < TOK) best[gid] = 0xFFFFFFFFFFFFFFFFULL;
    int t = gid >> 6;                                // wave per token
    int lane = threadIdx.x & 63;
    float4 v = *(const float4*)(x + (size_t)t * DD + lane * 4);
    f16x4 h, l;
    float s;
    s = v.x * SCALE; h.x = (f16)s; l.x = (f16)(s - (float)h.x);
    s = v.y * SCALE; h.y = (f16)s; l.y = (f16)(s - (float)h.y);
    s = v.z * SCALE; h.z = (f16)s; l.z = (f16)(s - (float)h.z);
    s = v.w * SCALE; h.w = (f16)s; l.w = (f16)(s - (float)h.w);
    *(f16x4*)(A + (size_t)t * 512 + lane * 4) = h;
    *(f16x4*)(A + (size_t)t * 512 + 256 + lane * 4) = l;
    float p = v.x * v.x + v.y * v.y + v.z * v.z + v.w * v.w;
#pragma unroll
    for (int off = 32; off > 0; off >>= 1) p += __shfl_down(p, off, 64);
    if (lane == 0) x2[t] = p;
}

// ---- transpose emb -> embT (fp32) + limb split -> B rows [eh(256)|el(256)] ----
__global__ void vq_trsplit_kernel(const float* __restrict__ emb, float* __restrict__ embT,
                                  f16* __restrict__ B) {
    __shared__ float tile[32][33];
    int tx = threadIdx.x & 31, ty = threadIdx.x >> 5;    // 32x8 threads
    int k0 = blockIdx.x * 32, d0 = blockIdx.y * 32;      // grid (256, 8)
#pragma unroll
    for (int j = 0; j < 4; j++) {
        int d = ty * 4 + j;
        tile[d][tx] = emb[(size_t)(d0 + d) * KK + k0 + tx];
    }
    __syncthreads();
#pragma unroll
    for (int j = 0; j < 4; j++) {
        int k = ty * 4 + j;
        float v = tile[tx][k];
        embT[(size_t)(k0 + k) * DD + d0 + tx] = v;
        float sv = v * SCALE;
        f16 h = (f16)sv;
        B[(size_t)(k0 + k) * 512 + d0 + tx] = h;
        B[(size_t)(k0 + k) * 512 + 256 + d0 + tx] = (f16)(sv - (float)h);
    }
}

// global->LDS 16B, offset ALWAYS baked into the pointer (r11 lesson: the
// builtin's offset immediate is NOT equivalent and breaks correctness).
__device__ __forceinline__ void gl(const char* g, char* l) {
    __builtin_amdgcn_global_load_lds(
        (const __attribute__((address_space(1))) unsigned int*)g,
        (__attribute__((address_space(3))) unsigned int*)l, 16, 0, 0);
}

// ---------------- fused distance + argmin: m201 8-phase, K=768 GEMM ----------
// Schedule identical to round 9 (refcheck-passed). Staging via RUNNING POINTERS
// advanced by literal deltas after each site (A: +128x7, -896 @ kt7->8, +128x3;
// B: -384 @ kt3->4, else +128) -> 16 VGPRs of address state, no LICM hoisting
// (sequential dep chain), asm pin blocks reassociation. Kills the r8/r9 spill.
__global__ __launch_bounds__(512, 2) void vq_argmin_kernel(
        const f16* __restrict__ Ag, const f16* __restrict__ Bg,
        const float* __restrict__ x2, const float* __restrict__ e2,
        u64* __restrict__ best) {
    extern __shared__ char lds[];          // 131072

    const int tid = threadIdx.x;
    const int lane = tid & 63;
    const int wid = tid >> 6;              // 8 waves: wr (2) x wc (4)
    const int wr = wid >> 2;
    const int wc = wid & 3;
    const int lrow = lane & 15;
    const int kg = lane >> 4;
    const int k0 = blockIdx.x * BN;        // grid (32, 64)
    const int t0 = blockIdx.y * BM;

    // ds_read: swizzled 16B slot offsets for ksteps 0/1 (slot = ks*4+kg)
    const int sl0 = ((kg)     ^ (lrow & 7)) << 4;
    const int sl1 = ((4 + kg) ^ (lrow & 7)) << 4;
    const int ardo = wr * 16384 + lrow * 128;           // + mh*8192 + mc*2048
    const int brdo = 32768 + (wc * 32 + lrow) * 128;    // + nh*16384 + nc*2048

    // staging: per-thread source bases (pre-swizzled) + LDS dest offsets.
    const int row = tid >> 3;                           // 0..63
    const int ksw16 = ((tid & 7) ^ (row & 7)) << 4;
    const unsigned tid16 = tid << 4;
    const char* Asrc = (const char*)Ag + (size_t)(t0 + row) * 1024 + ksw16;
    const char* Bs0 = (const char*)Bg +
        (size_t)(k0 + ((row >> 5)) * 64 + (row & 31)) * 1024 + ksw16;
    const char* Bs1 = (const char*)Bg +
        (size_t)(k0 + (2 + (row >> 5)) * 64 + (row & 31)) * 1024 + ksw16;

    // running staging pointers (tile 0 positions) + LDS dest offsets
    const char* Aq[4];
    const char* Bq[4];
    unsigned AdstQ[2][4], BdstQ[2][4];
#pragma unroll
    for (int qa = 0; qa < 4; qa++) {
        Aq[qa] = Asrc + qa * 65536;
        AdstQ[0][qa] = qa * 8192 + tid16;
        AdstQ[1][qa] = 65536 + qa * 8192 + tid16;
    }
#pragma unroll
    for (int g = 0; g < 2; g++)
#pragma unroll
        for (int nh = 0; nh < 2; nh++) {
            Bq[g * 2 + nh] = (g ? Bs1 : Bs0) + nh * 32768;
            BdstQ[0][g * 2 + nh] = 32768 + nh * 16384 + g * 8192 + tid16;
            BdstQ[1][g * 2 + nh] = 98304 + nh * 16384 + g * 8192 + tid16;
        }

// stage quarter, then advance its running pointer (literal delta, pinned)
#define STAGE_A(qa, kt, b) { gl(Aq[qa], lds + AdstQ[b][qa]); \
    Aq[qa] += (((kt) == 7) ? -896 : 128); asm("" : "+v"(Aq[qa])); }
#define STAGE_B(nh, g, kt, b) { gl(Bq[(g)*2+(nh)], lds + BdstQ[b][(g)*2+(nh)]); \
    Bq[(g)*2+(nh)] += (((kt) == 3) ? -384 : 128); asm("" : "+v"(Bq[(g)*2+(nh)])); }
#define MF(x, y, z) __builtin_amdgcn_mfma_f32_16x16x32_f16(x, y, z, 0, 0, 0)
#define BARR __builtin_amdgcn_s_barrier()
#define WLG0 asm volatile("s_waitcnt lgkmcnt(0)" ::: "memory")
#define PRIO1 __builtin_amdgcn_s_setprio(1)
#define PRIO0 __builtin_amdgcn_s_setprio(0)
#define LDA(mh) { const char* _p = cb + ardo + (mh)*8192; \
    af[0][0]=*(const f16x8*)(_p+sl0);      af[0][1]=*(const f16x8*)(_p+sl1); \
    af[1][0]=*(const f16x8*)(_p+2048+sl0); af[1][1]=*(const f16x8*)(_p+2048+sl1); \
    af[2][0]=*(const f16x8*)(_p+4096+sl0); af[2][1]=*(const f16x8*)(_p+4096+sl1); \
    af[3][0]=*(const f16x8*)(_p+6144+sl0); af[3][1]=*(const f16x8*)(_p+6144+sl1); }
#define LDB(nh) { const char* _p = cb + brdo + (nh)*16384; \
    bf[0][0]=*(const f16x8*)(_p+sl0);      bf[0][1]=*(const f16x8*)(_p+sl1); \
    bf[1][0]=*(const f16x8*)(_p+2048+sl0); bf[1][1]=*(const f16x8*)(_p+2048+sl1); }
#define MMQ(MB, NB) { \
    acc[MB][NB]    =MF(af[0][0],bf[0][0],acc[MB][NB]);     acc[MB][NB]    =MF(af[0][1],bf[0][1],acc[MB][NB]); \
    acc[MB][NB+1]  =MF(af[0][0],bf[1][0],acc[MB][NB+1]);   acc[MB][NB+1]  =MF(af[0][1],bf[1][1],acc[MB][NB+1]); \
    acc[MB+1][NB]  =MF(af[1][0],bf[0][0],acc[MB+1][NB]);   acc[MB+1][NB]  =MF(af[1][1],bf[0][1],acc[MB+1][NB]); \
    acc[MB+1][NB+1]=MF(af[1][0],bf[1][0],acc[MB+1][NB+1]); acc[MB+1][NB+1]=MF(af[1][1],bf[1][1],acc[MB+1][NB+1]); \
    acc[MB+2][NB]  =MF(af[2][0],bf[0][0],acc[MB+2][NB]);   acc[MB+2][NB]  =MF(af[2][1],bf[0][1],acc[MB+2][NB]); \
    acc[MB+2][NB+1]=MF(af[2][0],bf[1][0],acc[MB+2][NB+1]); acc[MB+2][NB+1]=MF(af[2][1],bf[1][1],acc[MB+2][NB+1]); \
    acc[MB+3][NB]  =MF(af[3][0],bf[0][0],acc[MB+3][NB]);   acc[MB+3][NB]  =MF(af[3][1],bf[0][1],acc[MB+3][NB]); \
    acc[MB+3][NB+1]=MF(af[3][0],bf[1][0],acc[MB+3][NB+1]); acc[MB+3][NB+1]=MF(af[3][1],bf[1][1],acc[MB+3][NB+1]); }

    f32x4 acc[8][4];
#pragma unroll
    for (int m = 0; m < 8; m++)
#pragma unroll
        for (int n = 0; n < 4; n++) {
            f32x4 z = {0.0f, 0.0f, 0.0f, 0.0f};
            acc[m][n] = z;
        }
    f16x8 af[4][2], bf[2][2];

    // prologue: tile0 full (8) -> buf0, tile1 A quarters (4) -> buf1
    STAGE_A(0, 0, 0); STAGE_A(1, 0, 0); STAGE_A(2, 0, 0); STAGE_A(3, 0, 0);
    STAGE_B(0, 0, 0, 0); STAGE_B(0, 1, 0, 0); STAGE_B(1, 0, 0, 0); STAGE_B(1, 1, 0, 0);
    STAGE_A(0, 1, 1); STAGE_A(1, 1, 1); STAGE_A(2, 1, 1); STAGE_A(3, 1, 1);
    asm volatile("s_waitcnt vmcnt(4)" ::: "memory");
    BARR;

#pragma unroll
    for (int i = 0; i < NIT; i++) {
        const int ktb = 2 * i + 1, kt2 = 2 * i + 2, kt3 = 2 * i + 3;
        const bool st = (i < NIT - 1);
        const char* cb = lds;                      // ---- even tile, buf0 ----
        // P1 (m0,n0)
        LDA(0); LDB(0);
        STAGE_B(1, 0, ktb, 1); STAGE_B(1, 1, ktb, 1);
        asm volatile("s_waitcnt lgkmcnt(8)" ::: "memory");
        BARR; WLG0; PRIO1; MMQ(0, 0); PRIO0; BARR;
        // P2 (m0,n1)
        LDB(1);
        STAGE_B(0, 0, ktb, 1); STAGE_B(0, 1, ktb, 1);
        if (st) { STAGE_A(0, kt2, 0); STAGE_A(2, kt2, 0); }
        BARR; WLG0; PRIO1; MMQ(0, 2); PRIO0; BARR;
        // P3 (m1,n1)
        LDA(1);
        BARR; WLG0; PRIO1; MMQ(4, 2); PRIO0; BARR;
        // P4 (m1,n0) + tile boundary (counted vmcnt)
        LDB(0);
        if (st) { STAGE_A(1, kt2, 0); STAGE_A(3, kt2, 0); }
        BARR; WLG0; PRIO1; MMQ(4, 0); PRIO0;
        if (st) asm volatile("s_waitcnt vmcnt(4)" ::: "memory");
        else    asm volatile("s_waitcnt vmcnt(0)" ::: "memory");
        BARR;

        cb = lds + 65536;                          // ---- odd tile, buf1 ----
        // P5 (m0,n0)
        LDA(0); LDB(0);
        if (st) { STAGE_B(1, 0, kt2, 0); STAGE_B(1, 1, kt2, 0); }
        asm volatile("s_waitcnt lgkmcnt(8)" ::: "memory");
        BARR; WLG0; PRIO1; MMQ(0, 0); PRIO0; BARR;
        // P6 (m0,n1)
        LDB(1);
        if (st) { STAGE_B(0, 0, kt2, 0); STAGE_B(0, 1, kt2, 0); }
        BARR; WLG0; PRIO1; MMQ(0, 2); PRIO0; BARR;
        // P7 (m1,n1)
        LDA(1);
        if (st) { STAGE_A(0, kt3, 1); STAGE_A(2, kt3, 1); }
        BARR; WLG0; PRIO1; MMQ(4, 2); PRIO0; BARR;
        // P8 (m1,n0) + boundary
        LDB(0);
        if (st) { STAGE_A(1, kt3, 1); STAGE_A(3, kt3, 1); }
        BARR; WLG0; PRIO1; MMQ(4, 0); PRIO0;
        if (st) asm volatile("s_waitcnt vmcnt(4)" ::: "memory");
        BARR;
    }
#undef STAGE_A
#undef STAGE_B

    // ---------------- epilogue: distances + argmin ----------------
    // C/D: col = lane&15, row = (lane>>4)*4 + reg; cell (m,n): rows wr*128 +
    // (m>>2)*64 + (m&3)*16, cols wc*64 + (n>>1)*32 + (n&1)*16.
    __syncthreads();
    u64* red = (u64*)lds;
    if (tid < BM) red[tid] = 0xFFFFFFFFFFFFFFFFULL;
    __syncthreads();

    float se2[4];
#pragma unroll
    for (int n = 0; n < 4; n++)
        se2[n] = e2[k0 + wc * 64 + (n >> 1) * 32 + (n & 1) * 16 + lrow];

#pragma unroll
    for (int m = 0; m < 8; m++) {
#pragma unroll
        for (int r = 0; r < 4; r++) {
            int rowl = wr * 128 + (m >> 2) * 64 + (m & 3) * 16 + kg * 4 + r;
            float sx2 = x2[t0 + rowl];
            u64 b = 0xFFFFFFFFFFFFFFFFULL;
#pragma unroll
            for (int n = 0; n < 4; n++) {
                int kgl = k0 + wc * 64 + (n >> 1) * 32 + (n & 1) * 16 + lrow;
                float s = sx2 + se2[n];            // rounded add (matches ref)
                float td = acc[m][n][r] * DESCALE; // exact pow2 scale
                asm volatile("" : "+v"(td));
                float dist = s - td;               // rounded sub (matches ref)
                u64 pk = ((u64)__float_as_uint(dist) << 32) | (unsigned)kgl;
                b = pk < b ? pk : b;
            }
#pragma unroll
            for (int off2 = 1; off2 < 16; off2 <<= 1) {
                u64 o = __shfl_xor(b, off2, 64);
                b = o < b ? o : b;
            }
            if (lrow == 0) atomicMin(&red[rowl], b);
        }
    }
    __syncthreads();
    if (tid < BM) atomicMin(&best[t0 + tid], red[tid]);
}

// ---------------- extract indices + counts ----------------
__global__ void vq_indices_kernel(const u64* __restrict__ best, int* __restrict__ indices,
                                  int* __restrict__ counts) {
    int t = blockIdx.x * 256 + threadIdx.x;
    int idx = (int)(best[t] & 0xFFFFFFFFULL);
    indices[t] = idx;
    atomicAdd(&counts[idx], 1);
}

// ---------------- new_N + N_sum ----------------
__global__ void vq_newN_kernel(const float* __restrict__ N, const int* __restrict__ counts,
                               float* __restrict__ outN, float* __restrict__ nsum) {
    int k = blockIdx.x * 256 + threadIdx.x;
    float a = 0.99f * N[k];
    float b = 0.01f * (float)counts[k];
    float nN = a + b;
    outN[k] = nN;
    float s = nN;
#pragma unroll
    for (int off = 32; off > 0; off >>= 1) s += __shfl_down(s, off, 64);
    __shared__ float wsum[4];
    int lane = threadIdx.x & 63, w = threadIdx.x >> 6;
    if (lane == 0) wsum[w] = s;
    __syncthreads();
    if (threadIdx.x == 0) atomicAdd(nsum, wsum[0] + wsum[1] + wsum[2] + wsum[3]);
}

// ---------------- fused: quantized_st write + sums scatter ----------------
__global__ void vq_gs_kernel(const float* __restrict__ x, const float* __restrict__ embT,
                             const int* __restrict__ indices, float* __restrict__ out0,
                             float* __restrict__ sums) {
    int t = blockIdx.x * 4 + (threadIdx.x >> 6);     // 4096 blocks, wave per token
    int lane = threadIdx.x & 63;
    int idx = indices[t];
    size_t o = (size_t)t * DD + lane * 4;
    float4 xv = *(const float4*)(x + o);
    float4 qv = *(const float4*)(embT + (size_t)idx * DD + lane * 4);
    float4 ov;
    ov.x = xv.x + (qv.x - xv.x);
    ov.y = xv.y + (qv.y - xv.y);
    ov.z = xv.z + (qv.z - xv.z);
    ov.w = xv.w + (qv.w - xv.w);
    *(float4*)(out0 + o) = ov;
    float* base = sums + (size_t)idx * DD + lane * 4;
    atomicAdd(base + 0, xv.x);
    atomicAdd(base + 1, xv.y);
    atomicAdd(base + 2, xv.z);
    atomicAdd(base + 3, xv.w);
}

// ---------------- new_m and new_embeddings ----------------
__global__ void vq_final_kernel(const float* __restrict__ m, const float* __restrict__ sums,
                                const float* __restrict__ outN, const float* __restrict__ nsum,
                                float* __restrict__ outEmb, float* __restrict__ outM) {
    int gid = blockIdx.x * 256 + threadIdx.x;
    int k = gid & (KK - 1);
    int d = gid >> 13;
    float Nsum = *nsum;
    float nN = outN[k];
    float scaled = (nN + 1e-5f) / (Nsum + 0.08192f) * Nsum;
    float a = 0.99f * m[gid];
    float b = 0.01f * sums[(size_t)k * DD + d];
    float mv = a + b;
    outM[gid] = mv;
    outEmb[gid] = mv / scaled;
}

extern "C" void kernel_launch(void* const* d_in, const int* in_sizes, int n_in,
                              void* d_out, int out_size, void* d_ws, size_t ws_size,
                              hipStream_t stream) {
    const float* x   = (const float*)d_in[0];   // [16384][256]
    const float* emb = (const float*)d_in[1];   // [256][8192]
    const float* Nin = (const float*)d_in[2];   // [8192]
    const float* min = (const float*)d_in[3];   // [256][8192]

    float* out0   = (float*)d_out;              // quantized_st  [4194304]
    float* outEmb = out0 + 4194304;             // new_embeddings [2097152]
    float* outN   = outEmb + 2097152;           // new_N [8192]
    float* outM   = outN + 8192;                // new_m [2097152]

    // workspace (floats)
    float* ws      = (float*)d_ws;
    float* sums    = ws;                        // 2097152
    float* e2buf   = ws + 2097152;              // 8192
    float* x2buf   = e2buf + 8192;              // 16384
    u64*   best    = (u64*)(x2buf + 16384);     // 16384 u64
    int*   idxbuf  = (int*)(best + 16384);      // 16384
    int*   counts  = idxbuf + 16384;            // 8192
    float* nsum    = (float*)(counts + 8192);   // 1

    // GEMM operand panels staged in output regions written later:
    f16* Ab   = (f16*)out0;                     // [16384][512] = [xh|xl], 16 MB
    f16* Bb   = (f16*)outEmb;                   // [8192][512]  = [eh|el],  8 MB
    float* embT = outM;                         // 8 MB fp32, overwritten last

    vq_e2_kernel<<<32, 256, 0, stream>>>(emb, e2buf, counts, nsum);
    vq_x2split_kernel<<<4096, 256, 0, stream>>>(x, x2buf, Ab, sums, best);
    vq_trsplit_kernel<<<dim3(256, 8), 256, 0, stream>>>(emb, embT, Bb);
    vq_argmin_kernel<<<dim3(KK / BN, TOK / BM), 512, 131072, stream>>>(
        Ab, Bb, x2buf, e2buf, best);
    vq_indices_kernel<<<64, 256, 0, stream>>>(best, idxbuf, counts);
    vq_newN_kernel<<<32, 256, 0, stream>>>(Nin, counts, outN, nsum);
    vq_gs_kernel<<<4096, 256, 0, stream>>>(x, embT, idxbuf, out0, sums);
    vq_final_kernel<<<8192, 256, 0, stream>>>(min, sums, outN, nsum, outEmb, outM);
}